// Round 2
// baseline (1175.149 us; speedup 1.0000x reference)
//
#include <hip/hip_runtime.h>
#include <math.h>

#define BN_EPS 1e-5f

__device__ inline float4 f4add(float4 a, float4 b) {
  return make_float4(a.x + b.x, a.y + b.y, a.z + b.z, a.w + b.w);
}

// ---------------- CSR build ----------------

__global__ void count_kernel(const int* __restrict__ dst, int* __restrict__ cnt, int e) {
  int i = blockIdx.x * 256 + threadIdx.x;
  int stride = gridDim.x * 256;
  for (; i < e; i += stride) atomicAdd(&cnt[dst[i]], 1);
}

__global__ void dinv_kernel(const int* __restrict__ cnt, float* __restrict__ dinv, int n) {
  int i = blockIdx.x * 256 + threadIdx.x;
  if (i < n) dinv[i] = rsqrtf((float)(cnt[i] + 1));  // +1 self loop
}

__global__ void scan_block_sums(const int* __restrict__ cnt, int* __restrict__ partial, int n) {
  __shared__ int sdata[256];
  int base = blockIdx.x * 1024;
  int s = 0;
  for (int i = threadIdx.x; i < 1024; i += 256) {
    int idx = base + i;
    s += (idx < n) ? cnt[idx] : 0;
  }
  sdata[threadIdx.x] = s;
  __syncthreads();
  for (int off = 128; off > 0; off >>= 1) {
    if (threadIdx.x < off) sdata[threadIdx.x] += sdata[threadIdx.x + off];
    __syncthreads();
  }
  if (threadIdx.x == 0) partial[blockIdx.x] = sdata[0];
}

__global__ void scan_partials(int* __restrict__ partial, int nb,
                              int* __restrict__ row_start, int n, int e) {
  if (blockIdx.x == 0 && threadIdx.x == 0) {
    int acc = 0;
    for (int i = 0; i < nb; i++) { int v = partial[i]; partial[i] = acc; acc += v; }
    row_start[n] = e;
  }
}

__global__ void scan_write(const int* __restrict__ cnt, const int* __restrict__ partial,
                           int* __restrict__ row_start, int* __restrict__ cursor, int n) {
  __shared__ int tsum[256];
  int base = blockIdx.x * 1024 + threadIdx.x * 4;
  int v[4]; int s = 0;
#pragma unroll
  for (int j = 0; j < 4; j++) { int idx = base + j; v[j] = (idx < n) ? cnt[idx] : 0; s += v[j]; }
  tsum[threadIdx.x] = s;
  __syncthreads();
  for (int off = 1; off < 256; off <<= 1) {
    int add = (threadIdx.x >= off) ? tsum[threadIdx.x - off] : 0;
    __syncthreads();
    tsum[threadIdx.x] += add;
    __syncthreads();
  }
  int excl = partial[blockIdx.x] + ((threadIdx.x > 0) ? tsum[threadIdx.x - 1] : 0);
#pragma unroll
  for (int j = 0; j < 4; j++) {
    int idx = base + j;
    if (idx < n) { row_start[idx] = excl; cursor[idx] = excl; }
    excl += v[j];
  }
}

__global__ void fill_kernel(const int* __restrict__ src, const int* __restrict__ dst,
                            int* __restrict__ cursor, int* __restrict__ csr_src, int e) {
  int i = blockIdx.x * 256 + threadIdx.x;
  int stride = gridDim.x * 256;
  for (; i < e; i += stride) {
    int p = atomicAdd(&cursor[dst[i]], 1);
    csr_src[p] = src[i];
  }
}

// ---------------- per-layer kernels ----------------

// hh[n,c] = dinv[n] * sum_k X[n,k] * W[k,c]
template <int K, int C, int LOGC>
__global__ void matmul_dinv(const float* __restrict__ X, const float* __restrict__ W,
                            const float* __restrict__ dinv, float* __restrict__ hh, int n) {
  __shared__ float w[K * C];
  for (int i = threadIdx.x; i < K * C; i += 256) w[i] = W[i];
  __syncthreads();
  int idx = blockIdx.x * 256 + threadIdx.x;
  int total = n * C;
  if (idx >= total) return;
  int nn = idx >> LOGC;
  int c = idx & (C - 1);
  float acc = 0.f;
#pragma unroll
  for (int k = 0; k < K; k++) acc += X[nn * K + k] * w[k * C + c];
  hh[idx] = acc * dinv[nn];
}

// act[n, c4*4..+3] = relu(dinv[n]*(hh[n] + sum_{j in row(n)} hh[src_j]) + b)
// float4-vectorized: GP = C/4 lanes per node, 4-wide unrolled edge loop for MLP.
// Accumulates per-channel sum / sumsq for BatchNorm into stats[0..C) / stats[C..2C).
template <int C, int LOGGP>
__global__ void gather_finalize(const float4* __restrict__ hh4, const int* __restrict__ row_start,
                                const int* __restrict__ csr_src, const float* __restrict__ dinv,
                                const float* __restrict__ bias, float4* __restrict__ act4,
                                float* __restrict__ stats, int n) {
  constexpr int GP = C / 4;       // float4 groups per node
  constexpr int NPB = 256 / GP;   // nodes per block
  int tid = threadIdx.x;
  int c4 = tid & (GP - 1);
  int local = tid >> LOGGP;
  int n0 = blockIdx.x * NPB + local;

  float4 lsum = make_float4(0.f, 0.f, 0.f, 0.f);
  float4 lsq = make_float4(0.f, 0.f, 0.f, 0.f);

  if (n0 < n) {
    float4 acc = hh4[n0 * GP + c4];  // self term
    int s = row_start[n0], e0 = row_start[n0 + 1];
    int j = s;
    float4 a0 = make_float4(0.f, 0.f, 0.f, 0.f);
    float4 a1 = a0, a2 = a0, a3 = a0;
    for (; j + 4 <= e0; j += 4) {
      int i0 = csr_src[j];
      int i1 = csr_src[j + 1];
      int i2 = csr_src[j + 2];
      int i3 = csr_src[j + 3];
      float4 v0 = hh4[i0 * GP + c4];
      float4 v1 = hh4[i1 * GP + c4];
      float4 v2 = hh4[i2 * GP + c4];
      float4 v3 = hh4[i3 * GP + c4];
      a0 = f4add(a0, v0);
      a1 = f4add(a1, v1);
      a2 = f4add(a2, v2);
      a3 = f4add(a3, v3);
    }
    for (; j < e0; j++) {
      int i0 = csr_src[j];
      acc = f4add(acc, hh4[i0 * GP + c4]);
    }
    acc = f4add(acc, f4add(f4add(a0, a1), f4add(a2, a3)));

    float dn = dinv[n0];
    float4 b4 = ((const float4*)bias)[c4];
    float4 v;
    v.x = fmaxf(dn * acc.x + b4.x, 0.f);
    v.y = fmaxf(dn * acc.y + b4.y, 0.f);
    v.z = fmaxf(dn * acc.z + b4.z, 0.f);
    v.w = fmaxf(dn * acc.w + b4.w, 0.f);
    act4[n0 * GP + c4] = v;
    lsum = v;
    lsq = make_float4(v.x * v.x, v.y * v.y, v.z * v.z, v.w * v.w);
  }

  __shared__ float4 redS[256];
  __shared__ float4 redQ[256];
  redS[tid] = lsum;
  redQ[tid] = lsq;
  __syncthreads();
#pragma unroll
  for (int off = 128; off >= GP; off >>= 1) {
    if (tid < off) {
      redS[tid] = f4add(redS[tid], redS[tid + off]);
      redQ[tid] = f4add(redQ[tid], redQ[tid + off]);
    }
    __syncthreads();
  }
  if (tid < GP) {
    atomicAdd(&stats[4 * tid + 0], redS[tid].x);
    atomicAdd(&stats[4 * tid + 1], redS[tid].y);
    atomicAdd(&stats[4 * tid + 2], redS[tid].z);
    atomicAdd(&stats[4 * tid + 3], redS[tid].w);
    atomicAdd(&stats[C + 4 * tid + 0], redQ[tid].x);
    atomicAdd(&stats[C + 4 * tid + 1], redQ[tid].y);
    atomicAdd(&stats[C + 4 * tid + 2], redQ[tid].z);
    atomicAdd(&stats[C + 4 * tid + 3], redQ[tid].w);
  }
}

// y = elu((v - mean)*rsqrt(var+eps)*g + bt), in place
template <int C>
__global__ void bn_elu(float* __restrict__ act, const float* __restrict__ stats,
                       const float* __restrict__ g, const float* __restrict__ bt, int n) {
  int i = blockIdx.x * 256 + threadIdx.x;
  int total = n * C;
  if (i >= total) return;
  int c = i & (C - 1);
  float inv_n = 1.0f / (float)n;
  float m = stats[c] * inv_n;
  float var = stats[C + c] * inv_n - m * m;
  var = fmaxf(var, 0.f);
  float sc = rsqrtf(var + BN_EPS) * g[c];
  float v = (act[i] - m) * sc + bt[c];
  act[i] = v > 0.f ? v : (expf(v) - 1.f);  // ELU
}

// ---------------- MLP head + log_softmax ----------------

__global__ void head_kernel(const float* __restrict__ h,
                            const float* __restrict__ Wf1, const float* __restrict__ bf1,
                            const float* __restrict__ Wf2, const float* __restrict__ bf2,
                            const float* __restrict__ Wf3, const float* __restrict__ bf3,
                            float* __restrict__ out, int n) {
  __shared__ float w1[64 * 32], w2[32 * 16], w3[16 * 2];
  __shared__ float sb1[32], sb2[16], sb3[2];
  for (int i = threadIdx.x; i < 64 * 32; i += 256) w1[i] = Wf1[i];
  for (int i = threadIdx.x; i < 32 * 16; i += 256) w2[i] = Wf2[i];
  if (threadIdx.x < 32) {
    w3[threadIdx.x] = Wf3[threadIdx.x];
    sb1[threadIdx.x] = bf1[threadIdx.x];
  }
  if (threadIdx.x < 16) sb2[threadIdx.x] = bf2[threadIdx.x];
  if (threadIdx.x < 2) sb3[threadIdx.x] = bf3[threadIdx.x];
  __syncthreads();

  int n0 = blockIdx.x * 256 + threadIdx.x;
  if (n0 >= n) return;

  float hv[64];
#pragma unroll
  for (int k = 0; k < 64; k++) hv[k] = h[n0 * 64 + k];

  float a1[32];
#pragma unroll
  for (int c = 0; c < 32; c++) {
    float acc = sb1[c];
#pragma unroll
    for (int k = 0; k < 64; k++) acc += hv[k] * w1[k * 32 + c];
    a1[c] = acc > 0.f ? acc : (expf(acc) - 1.f);
  }
  float a2[16];
#pragma unroll
  for (int c = 0; c < 16; c++) {
    float acc = sb2[c];
#pragma unroll
    for (int k = 0; k < 32; k++) acc += a1[k] * w2[k * 16 + c];
    a2[c] = acc > 0.f ? acc : (expf(acc) - 1.f);
  }
  float z0 = sb3[0], z1 = sb3[1];
#pragma unroll
  for (int k = 0; k < 16; k++) {
    z0 += a2[k] * w3[k * 2 + 0];
    z1 += a2[k] * w3[k * 2 + 1];
  }
  float mx = fmaxf(z0, z1);
  float lse = mx + logf(expf(z0 - mx) + expf(z1 - mx));
  out[n0 * 2 + 0] = z0 - lse;
  out[n0 * 2 + 1] = z1 - lse;
}

// ---------------- launch ----------------

extern "C" void kernel_launch(void* const* d_in, const int* in_sizes, int n_in,
                              void* d_out, int out_size, void* d_ws, size_t ws_size,
                              hipStream_t stream) {
  const float* x = (const float*)d_in[0];
  const int* ei = (const int*)d_in[1];
  const float* W1 = (const float*)d_in[2];  const float* b1 = (const float*)d_in[3];
  const float* g1 = (const float*)d_in[4];  const float* bt1 = (const float*)d_in[5];
  const float* W2 = (const float*)d_in[6];  const float* b2 = (const float*)d_in[7];
  const float* g2 = (const float*)d_in[8];  const float* bt2 = (const float*)d_in[9];
  const float* W3 = (const float*)d_in[10]; const float* b3 = (const float*)d_in[11];
  const float* g3 = (const float*)d_in[12]; const float* bt3 = (const float*)d_in[13];
  const float* Wf1 = (const float*)d_in[14]; const float* bf1 = (const float*)d_in[15];
  const float* Wf2 = (const float*)d_in[16]; const float* bf2 = (const float*)d_in[17];
  const float* Wf3 = (const float*)d_in[18]; const float* bf3 = (const float*)d_in[19];
  float* out = (float*)d_out;

  const int N = in_sizes[0] / 4;
  const int E = in_sizes[1] / 2;
  const int* srcp = ei;
  const int* dstp = ei + E;
  const int NB = (N + 1023) / 1024;

  char* ws = (char*)d_ws;
  size_t off = 0;
  auto alloc = [&](size_t bytes) {
    off = (off + 255) & ~(size_t)255;
    size_t o = off;
    off += bytes;
    return o;
  };
  int*   cnt       = (int*)  (ws + alloc((size_t)N * 4));
  float* dinv      = (float*)(ws + alloc((size_t)N * 4));
  int*   row_start = (int*)  (ws + alloc((size_t)(N + 1) * 4));
  int*   cursor    = (int*)  (ws + alloc((size_t)N * 4));
  int*   partial   = (int*)  (ws + alloc((size_t)NB * 4));
  int*   csr_src   = (int*)  (ws + alloc((size_t)E * 4));
  float* stats     = (float*)(ws + alloc((size_t)224 * 4));  // 2*16 + 2*32 + 2*64
  float* bufA      = (float*)(ws + alloc((size_t)N * 64 * 4));
  float* bufB      = (float*)(ws + alloc((size_t)N * 64 * 4));
  float* st1 = stats;       // [32]
  float* st2 = stats + 32;  // [64]
  float* st3 = stats + 96;  // [128]

  hipMemsetAsync(cnt, 0, (size_t)N * 4, stream);
  hipMemsetAsync(stats, 0, 224 * 4, stream);

  int eb = (E + 255) / 256;
  int nb256 = (N + 255) / 256;

  count_kernel<<<eb, 256, 0, stream>>>(dstp, cnt, E);
  dinv_kernel<<<nb256, 256, 0, stream>>>(cnt, dinv, N);
  scan_block_sums<<<NB, 256, 0, stream>>>(cnt, partial, N);
  scan_partials<<<1, 64, 0, stream>>>(partial, NB, row_start, N, E);
  scan_write<<<NB, 256, 0, stream>>>(cnt, partial, row_start, cursor, N);
  fill_kernel<<<eb, 256, 0, stream>>>(srcp, dstp, cursor, csr_src, E);

  // Layer 1: [N,4] -> [N,16]; gather: GP=4, NPB=64
  matmul_dinv<4, 16, 4><<<(N * 16 + 255) / 256, 256, 0, stream>>>(x, W1, dinv, bufA, N);
  gather_finalize<16, 2><<<(N + 63) / 64, 256, 0, stream>>>(
      (const float4*)bufA, row_start, csr_src, dinv, b1, (float4*)bufB, st1, N);
  bn_elu<16><<<(N * 16 + 255) / 256, 256, 0, stream>>>(bufB, st1, g1, bt1, N);

  // Layer 2: [N,16] -> [N,32]; gather: GP=8, NPB=32
  matmul_dinv<16, 32, 5><<<(N * 32 + 255) / 256, 256, 0, stream>>>(bufB, W2, dinv, bufA, N);
  gather_finalize<32, 3><<<(N + 31) / 32, 256, 0, stream>>>(
      (const float4*)bufA, row_start, csr_src, dinv, b2, (float4*)bufB, st2, N);
  bn_elu<32><<<(N * 32 + 255) / 256, 256, 0, stream>>>(bufB, st2, g2, bt2, N);

  // Layer 3: [N,32] -> [N,64]; gather: GP=16, NPB=16
  matmul_dinv<32, 64, 6><<<(N * 64 + 255) / 256, 256, 0, stream>>>(bufB, W3, dinv, bufA, N);
  gather_finalize<64, 4><<<(N + 15) / 16, 256, 0, stream>>>(
      (const float4*)bufA, row_start, csr_src, dinv, b3, (float4*)bufB, st3, N);
  bn_elu<64><<<(N * 64 + 255) / 256, 256, 0, stream>>>(bufB, st3, g3, bt3, N);

  // MLP head + log_softmax
  head_kernel<<<nb256, 256, 0, stream>>>(bufB, Wf1, bf1, Wf2, bf2, Wf3, bf3, out, N);
}

// Round 3
// 432.729 us; speedup vs baseline: 2.7157x; 2.7157x over previous
//
#include <hip/hip_runtime.h>
#include <math.h>

#define BN_EPS 1e-5f

__device__ inline float4 f4add(float4 a, float4 b) {
  return make_float4(a.x + b.x, a.y + b.y, a.z + b.z, a.w + b.w);
}

// ---------------- CSR build ----------------

__global__ void count_kernel(const int* __restrict__ dst, int* __restrict__ cnt, int e) {
  int i = blockIdx.x * 256 + threadIdx.x;
  int stride = gridDim.x * 256;
  for (; i < e; i += stride) atomicAdd(&cnt[dst[i]], 1);
}

__global__ void dinv_kernel(const int* __restrict__ cnt, float* __restrict__ dinv, int n) {
  int i = blockIdx.x * 256 + threadIdx.x;
  if (i < n) dinv[i] = rsqrtf((float)(cnt[i] + 1));  // +1 self loop
}

__global__ void scan_block_sums(const int* __restrict__ cnt, int* __restrict__ partial, int n) {
  __shared__ int sdata[256];
  int base = blockIdx.x * 1024;
  int s = 0;
  for (int i = threadIdx.x; i < 1024; i += 256) {
    int idx = base + i;
    s += (idx < n) ? cnt[idx] : 0;
  }
  sdata[threadIdx.x] = s;
  __syncthreads();
  for (int off = 128; off > 0; off >>= 1) {
    if (threadIdx.x < off) sdata[threadIdx.x] += sdata[threadIdx.x + off];
    __syncthreads();
  }
  if (threadIdx.x == 0) partial[blockIdx.x] = sdata[0];
}

__global__ void scan_partials(int* __restrict__ partial, int nb,
                              int* __restrict__ row_start, int n, int e) {
  if (blockIdx.x == 0 && threadIdx.x == 0) {
    int acc = 0;
    for (int i = 0; i < nb; i++) { int v = partial[i]; partial[i] = acc; acc += v; }
    row_start[n] = e;
  }
}

__global__ void scan_write(const int* __restrict__ cnt, const int* __restrict__ partial,
                           int* __restrict__ row_start, int* __restrict__ cursor, int n) {
  __shared__ int tsum[256];
  int base = blockIdx.x * 1024 + threadIdx.x * 4;
  int v[4]; int s = 0;
#pragma unroll
  for (int j = 0; j < 4; j++) { int idx = base + j; v[j] = (idx < n) ? cnt[idx] : 0; s += v[j]; }
  tsum[threadIdx.x] = s;
  __syncthreads();
  for (int off = 1; off < 256; off <<= 1) {
    int add = (threadIdx.x >= off) ? tsum[threadIdx.x - off] : 0;
    __syncthreads();
    tsum[threadIdx.x] += add;
    __syncthreads();
  }
  int excl = partial[blockIdx.x] + ((threadIdx.x > 0) ? tsum[threadIdx.x - 1] : 0);
#pragma unroll
  for (int j = 0; j < 4; j++) {
    int idx = base + j;
    if (idx < n) { row_start[idx] = excl; cursor[idx] = excl; }
    excl += v[j];
  }
}

__global__ void fill_kernel(const int* __restrict__ src, const int* __restrict__ dst,
                            int* __restrict__ cursor, int* __restrict__ csr_src, int e) {
  int i = blockIdx.x * 256 + threadIdx.x;
  int stride = gridDim.x * 256;
  for (; i < e; i += stride) {
    int p = atomicAdd(&cursor[dst[i]], 1);
    csr_src[p] = src[i];
  }
}

// ---------------- per-layer kernels ----------------

// hh[n,c] = dinv[n] * sum_k X[n,k] * W[k,c]
template <int K, int C, int LOGC>
__global__ void matmul_dinv(const float* __restrict__ X, const float* __restrict__ W,
                            const float* __restrict__ dinv, float* __restrict__ hh, int n) {
  __shared__ float w[K * C];
  for (int i = threadIdx.x; i < K * C; i += 256) w[i] = W[i];
  __syncthreads();
  int idx = blockIdx.x * 256 + threadIdx.x;
  int total = n * C;
  if (idx >= total) return;
  int nn = idx >> LOGC;
  int c = idx & (C - 1);
  float acc = 0.f;
#pragma unroll
  for (int k = 0; k < K; k++) acc += X[nn * K + k] * w[k * C + c];
  hh[idx] = acc * dinv[nn];
}

// act[n, c4*4..+3] = relu(dinv[n]*(hh[n] + sum_{j in row(n)} hh[src_j]) + b)
// float4-vectorized, 4-wide unrolled edge loop. NO stats, NO LDS, NO atomics.
template <int C, int LOGGP>
__global__ void gather_finalize(const float4* __restrict__ hh4, const int* __restrict__ row_start,
                                const int* __restrict__ csr_src, const float* __restrict__ dinv,
                                const float* __restrict__ bias, float4* __restrict__ act4, int n) {
  constexpr int GP = C / 4;       // float4 groups per node
  constexpr int NPB = 256 / GP;   // nodes per block
  int tid = threadIdx.x;
  int c4 = tid & (GP - 1);
  int local = tid >> LOGGP;
  int n0 = blockIdx.x * NPB + local;
  if (n0 >= n) return;

  float4 acc = hh4[n0 * GP + c4];  // self term
  int s = row_start[n0], e0 = row_start[n0 + 1];
  int j = s;
  float4 a0 = make_float4(0.f, 0.f, 0.f, 0.f);
  float4 a1 = a0, a2 = a0, a3 = a0;
  for (; j + 4 <= e0; j += 4) {
    int i0 = csr_src[j];
    int i1 = csr_src[j + 1];
    int i2 = csr_src[j + 2];
    int i3 = csr_src[j + 3];
    float4 v0 = hh4[i0 * GP + c4];
    float4 v1 = hh4[i1 * GP + c4];
    float4 v2 = hh4[i2 * GP + c4];
    float4 v3 = hh4[i3 * GP + c4];
    a0 = f4add(a0, v0);
    a1 = f4add(a1, v1);
    a2 = f4add(a2, v2);
    a3 = f4add(a3, v3);
  }
  for (; j < e0; j++) {
    int i0 = csr_src[j];
    acc = f4add(acc, hh4[i0 * GP + c4]);
  }
  acc = f4add(acc, f4add(f4add(a0, a1), f4add(a2, a3)));

  float dn = dinv[n0];
  float4 b4 = ((const float4*)bias)[c4];
  float4 v;
  v.x = fmaxf(dn * acc.x + b4.x, 0.f);
  v.y = fmaxf(dn * acc.y + b4.y, 0.f);
  v.z = fmaxf(dn * acc.z + b4.z, 0.f);
  v.w = fmaxf(dn * acc.w + b4.w, 0.f);
  act4[n0 * GP + c4] = v;
}

// per-channel sum & sumsq of act -> stats[0..C), stats[C..2C).
// FIXED small grid: atomics = gridDim * 2C total (Guideline 12).
template <int C>
__global__ void stats_kernel(const float4* __restrict__ act4, float* __restrict__ stats, int n) {
  constexpr int GP = C / 4;
  constexpr int NPB = 256 / GP;
  int tid = threadIdx.x;
  int c4 = tid & (GP - 1);
  int local = tid >> 31 ? 0 : (tid / GP);  // tid/GP (GP is power of 2; compiler folds)
  float4 s = make_float4(0.f, 0.f, 0.f, 0.f);
  float4 q = make_float4(0.f, 0.f, 0.f, 0.f);
  for (int n0 = blockIdx.x * NPB + local; n0 < n; n0 += gridDim.x * NPB) {
    float4 v = act4[n0 * GP + c4];
    s = f4add(s, v);
    q.x += v.x * v.x; q.y += v.y * v.y; q.z += v.z * v.z; q.w += v.w * v.w;
  }
  __shared__ float4 redS[256];
  __shared__ float4 redQ[256];
  redS[tid] = s;
  redQ[tid] = q;
  __syncthreads();
#pragma unroll
  for (int off = 128; off >= GP; off >>= 1) {
    if (tid < off) {
      redS[tid] = f4add(redS[tid], redS[tid + off]);
      redQ[tid] = f4add(redQ[tid], redQ[tid + off]);
    }
    __syncthreads();
  }
  if (tid < GP) {
    atomicAdd(&stats[4 * tid + 0], redS[tid].x);
    atomicAdd(&stats[4 * tid + 1], redS[tid].y);
    atomicAdd(&stats[4 * tid + 2], redS[tid].z);
    atomicAdd(&stats[4 * tid + 3], redS[tid].w);
    atomicAdd(&stats[C + 4 * tid + 0], redQ[tid].x);
    atomicAdd(&stats[C + 4 * tid + 1], redQ[tid].y);
    atomicAdd(&stats[C + 4 * tid + 2], redQ[tid].z);
    atomicAdd(&stats[C + 4 * tid + 3], redQ[tid].w);
  }
}

// y = elu((v - mean)*rsqrt(var+eps)*g + bt), in place
template <int C>
__global__ void bn_elu(float* __restrict__ act, const float* __restrict__ stats,
                       const float* __restrict__ g, const float* __restrict__ bt, int n) {
  int i = blockIdx.x * 256 + threadIdx.x;
  int total = n * C;
  if (i >= total) return;
  int c = i & (C - 1);
  float inv_n = 1.0f / (float)n;
  float m = stats[c] * inv_n;
  float var = stats[C + c] * inv_n - m * m;
  var = fmaxf(var, 0.f);
  float sc = rsqrtf(var + BN_EPS) * g[c];
  float v = (act[i] - m) * sc + bt[c];
  act[i] = v > 0.f ? v : (expf(v) - 1.f);  // ELU
}

// ---------------- MLP head + log_softmax ----------------

__global__ void head_kernel(const float* __restrict__ h,
                            const float* __restrict__ Wf1, const float* __restrict__ bf1,
                            const float* __restrict__ Wf2, const float* __restrict__ bf2,
                            const float* __restrict__ Wf3, const float* __restrict__ bf3,
                            float* __restrict__ out, int n) {
  __shared__ float w1[64 * 32], w2[32 * 16], w3[16 * 2];
  __shared__ float sb1[32], sb2[16], sb3[2];
  for (int i = threadIdx.x; i < 64 * 32; i += 256) w1[i] = Wf1[i];
  for (int i = threadIdx.x; i < 32 * 16; i += 256) w2[i] = Wf2[i];
  if (threadIdx.x < 32) {
    w3[threadIdx.x] = Wf3[threadIdx.x];
    sb1[threadIdx.x] = bf1[threadIdx.x];
  }
  if (threadIdx.x < 16) sb2[threadIdx.x] = bf2[threadIdx.x];
  if (threadIdx.x < 2) sb3[threadIdx.x] = bf3[threadIdx.x];
  __syncthreads();

  int n0 = blockIdx.x * 256 + threadIdx.x;
  if (n0 >= n) return;

  float hv[64];
#pragma unroll
  for (int k = 0; k < 64; k++) hv[k] = h[n0 * 64 + k];

  float a1[32];
#pragma unroll
  for (int c = 0; c < 32; c++) {
    float acc = sb1[c];
#pragma unroll
    for (int k = 0; k < 64; k++) acc += hv[k] * w1[k * 32 + c];
    a1[c] = acc > 0.f ? acc : (expf(acc) - 1.f);
  }
  float a2[16];
#pragma unroll
  for (int c = 0; c < 16; c++) {
    float acc = sb2[c];
#pragma unroll
    for (int k = 0; k < 32; k++) acc += a1[k] * w2[k * 16 + c];
    a2[c] = acc > 0.f ? acc : (expf(acc) - 1.f);
  }
  float z0 = sb3[0], z1 = sb3[1];
#pragma unroll
  for (int k = 0; k < 16; k++) {
    z0 += a2[k] * w3[k * 2 + 0];
    z1 += a2[k] * w3[k * 2 + 1];
  }
  float mx = fmaxf(z0, z1);
  float lse = mx + logf(expf(z0 - mx) + expf(z1 - mx));
  out[n0 * 2 + 0] = z0 - lse;
  out[n0 * 2 + 1] = z1 - lse;
}

// ---------------- launch ----------------

extern "C" void kernel_launch(void* const* d_in, const int* in_sizes, int n_in,
                              void* d_out, int out_size, void* d_ws, size_t ws_size,
                              hipStream_t stream) {
  const float* x = (const float*)d_in[0];
  const int* ei = (const int*)d_in[1];
  const float* W1 = (const float*)d_in[2];  const float* b1 = (const float*)d_in[3];
  const float* g1 = (const float*)d_in[4];  const float* bt1 = (const float*)d_in[5];
  const float* W2 = (const float*)d_in[6];  const float* b2 = (const float*)d_in[7];
  const float* g2 = (const float*)d_in[8];  const float* bt2 = (const float*)d_in[9];
  const float* W3 = (const float*)d_in[10]; const float* b3 = (const float*)d_in[11];
  const float* g3 = (const float*)d_in[12]; const float* bt3 = (const float*)d_in[13];
  const float* Wf1 = (const float*)d_in[14]; const float* bf1 = (const float*)d_in[15];
  const float* Wf2 = (const float*)d_in[16]; const float* bf2 = (const float*)d_in[17];
  const float* Wf3 = (const float*)d_in[18]; const float* bf3 = (const float*)d_in[19];
  float* out = (float*)d_out;

  const int N = in_sizes[0] / 4;
  const int E = in_sizes[1] / 2;
  const int* srcp = ei;
  const int* dstp = ei + E;
  const int NB = (N + 1023) / 1024;

  char* ws = (char*)d_ws;
  size_t off = 0;
  auto alloc = [&](size_t bytes) {
    off = (off + 255) & ~(size_t)255;
    size_t o = off;
    off += bytes;
    return o;
  };
  int*   cnt       = (int*)  (ws + alloc((size_t)N * 4));
  float* dinv      = (float*)(ws + alloc((size_t)N * 4));
  int*   row_start = (int*)  (ws + alloc((size_t)(N + 1) * 4));
  int*   cursor    = (int*)  (ws + alloc((size_t)N * 4));
  int*   partial   = (int*)  (ws + alloc((size_t)NB * 4));
  int*   csr_src   = (int*)  (ws + alloc((size_t)E * 4));
  float* stats     = (float*)(ws + alloc((size_t)224 * 4));  // 2*16 + 2*32 + 2*64
  float* bufA      = (float*)(ws + alloc((size_t)N * 64 * 4));
  float* bufB      = (float*)(ws + alloc((size_t)N * 64 * 4));
  float* st1 = stats;       // [32]
  float* st2 = stats + 32;  // [64]
  float* st3 = stats + 96;  // [128]

  hipMemsetAsync(cnt, 0, (size_t)N * 4, stream);
  hipMemsetAsync(stats, 0, 224 * 4, stream);

  int eb = (E + 255) / 256;
  int nb256 = (N + 255) / 256;
  const int STATS_BLOCKS = 128;

  count_kernel<<<eb, 256, 0, stream>>>(dstp, cnt, E);
  dinv_kernel<<<nb256, 256, 0, stream>>>(cnt, dinv, N);
  scan_block_sums<<<NB, 256, 0, stream>>>(cnt, partial, N);
  scan_partials<<<1, 64, 0, stream>>>(partial, NB, row_start, N, E);
  scan_write<<<NB, 256, 0, stream>>>(cnt, partial, row_start, cursor, N);
  fill_kernel<<<eb, 256, 0, stream>>>(srcp, dstp, cursor, csr_src, E);

  // Layer 1: [N,4] -> [N,16]; gather: GP=4, NPB=64
  matmul_dinv<4, 16, 4><<<(N * 16 + 255) / 256, 256, 0, stream>>>(x, W1, dinv, bufA, N);
  gather_finalize<16, 2><<<(N + 63) / 64, 256, 0, stream>>>(
      (const float4*)bufA, row_start, csr_src, dinv, b1, (float4*)bufB, N);
  stats_kernel<16><<<STATS_BLOCKS, 256, 0, stream>>>((const float4*)bufB, st1, N);
  bn_elu<16><<<(N * 16 + 255) / 256, 256, 0, stream>>>(bufB, st1, g1, bt1, N);

  // Layer 2: [N,16] -> [N,32]; gather: GP=8, NPB=32
  matmul_dinv<16, 32, 5><<<(N * 32 + 255) / 256, 256, 0, stream>>>(bufB, W2, dinv, bufA, N);
  gather_finalize<32, 3><<<(N + 31) / 32, 256, 0, stream>>>(
      (const float4*)bufA, row_start, csr_src, dinv, b2, (float4*)bufB, N);
  stats_kernel<32><<<STATS_BLOCKS, 256, 0, stream>>>((const float4*)bufB, st2, N);
  bn_elu<32><<<(N * 32 + 255) / 256, 256, 0, stream>>>(bufB, st2, g2, bt2, N);

  // Layer 3: [N,32] -> [N,64]; gather: GP=16, NPB=16
  matmul_dinv<32, 64, 6><<<(N * 64 + 255) / 256, 256, 0, stream>>>(bufB, W3, dinv, bufA, N);
  gather_finalize<64, 4><<<(N + 15) / 16, 256, 0, stream>>>(
      (const float4*)bufA, row_start, csr_src, dinv, b3, (float4*)bufB, N);
  stats_kernel<64><<<STATS_BLOCKS, 256, 0, stream>>>((const float4*)bufB, st3, N);
  bn_elu<64><<<(N * 64 + 255) / 256, 256, 0, stream>>>(bufB, st3, g3, bt3, N);

  // MLP head + log_softmax
  head_kernel<<<nb256, 256, 0, stream>>>(bufB, Wf1, bf1, Wf2, bf2, Wf3, bf3, out, N);
}

// Round 4
// 333.460 us; speedup vs baseline: 3.5241x; 1.2977x over previous
//
#include <hip/hip_runtime.h>
#include <math.h>

#define BN_EPS 1e-5f

__device__ inline float4 f4add(float4 a, float4 b) {
  return make_float4(a.x + b.x, a.y + b.y, a.z + b.z, a.w + b.w);
}

// ---------------- bucketed CSR build ----------------
// bucket b = dst >> 8 (256 nodes per bucket). NBUCK = ceil(N/256) <= 512.

__global__ void hist_kernel(const int* __restrict__ dst, int* __restrict__ bcount, int e) {
  __shared__ int h[512];
  for (int i = threadIdx.x; i < 512; i += 256) h[i] = 0;
  __syncthreads();
  int stride = gridDim.x * 256;
  for (int i = blockIdx.x * 256 + threadIdx.x; i < e; i += stride)
    atomicAdd(&h[dst[i] >> 8], 1);
  __syncthreads();
  for (int i = threadIdx.x; i < 512; i += 256)
    if (h[i] > 0) atomicAdd(&bcount[i], h[i]);
}

// one block, 512 threads: exclusive scan of bcount -> boffset, bcursor; tails.
__global__ void scan_buckets(const int* __restrict__ bcount, int* __restrict__ boffset,
                             int* __restrict__ bcursor, int* __restrict__ row_start,
                             int nbuck, int n, int e) {
  __shared__ int sc[512];
  int tid = threadIdx.x;
  int v = (tid < nbuck) ? bcount[tid] : 0;
  sc[tid] = v;
  __syncthreads();
  for (int off = 1; off < 512; off <<= 1) {
    int add = (tid >= off) ? sc[tid - off] : 0;
    __syncthreads();
    sc[tid] += add;
    __syncthreads();
  }
  int excl = sc[tid] - v;
  if (tid <= nbuck) {
    int val = (tid < nbuck) ? excl : e;
    boffset[tid] = val;
    bcursor[tid] = val;
  }
  if (tid == 0) row_start[n] = e;
}

// each block owns a contiguous 4096-edge range; reserves per-bucket chunks and
// appends (src,dst) pairs -> ebuf. Writes are per-block sequential chunks.
__global__ void partition_kernel(const int* __restrict__ src, const int* __restrict__ dst,
                                 int* __restrict__ bcursor, int2* __restrict__ ebuf, int e) {
  __shared__ int h[512];
  __shared__ int base[512];
  const int BLK_E = 4096;
  int e0 = blockIdx.x * BLK_E;
  int e1 = min(e0 + BLK_E, e);
  for (int i = threadIdx.x; i < 512; i += 256) h[i] = 0;
  __syncthreads();
  for (int i = e0 + threadIdx.x; i < e1; i += 256)
    atomicAdd(&h[dst[i] >> 8], 1);
  __syncthreads();
  for (int i = threadIdx.x; i < 512; i += 256) {
    int c = h[i];
    base[i] = (c > 0) ? atomicAdd(&bcursor[i], c) : 0;
    h[i] = 0;  // reuse as within-block rank
  }
  __syncthreads();
  for (int i = e0 + threadIdx.x; i < e1; i += 256) {
    int d = dst[i];
    int b = d >> 8;
    int r = atomicAdd(&h[b], 1);
    ebuf[base[b] + r] = make_int2(src[i], d);
  }
}

// one block per bucket: LDS count + scan + cursor; emits row_start, dinv, csr_src.
__global__ void bucket_fill(const int2* __restrict__ ebuf, const int* __restrict__ boffset,
                            int* __restrict__ row_start, float* __restrict__ dinv,
                            int* __restrict__ csr_src, int n) {
  __shared__ int lcnt[256];
  __shared__ int lpre[256];
  int bid = blockIdx.x;
  int nb0 = bid << 8;
  int tid = threadIdx.x;
  int e0 = boffset[bid], e1 = boffset[bid + 1];
  lcnt[tid] = 0;
  __syncthreads();
  for (int j = e0 + tid; j < e1; j += 256)
    atomicAdd(&lcnt[ebuf[j].y - nb0], 1);
  __syncthreads();
  int v = lcnt[tid];
  lpre[tid] = v;
  __syncthreads();
  for (int off = 1; off < 256; off <<= 1) {
    int add = (tid >= off) ? lpre[tid - off] : 0;
    __syncthreads();
    lpre[tid] += add;
    __syncthreads();
  }
  int excl = lpre[tid] - v;
  int node = nb0 + tid;
  if (node < n) {
    row_start[node] = e0 + excl;
    dinv[node] = rsqrtf((float)(v + 1));  // +1 self loop
  }
  __syncthreads();
  lpre[tid] = excl;  // running cursor
  __syncthreads();
  for (int j = e0 + tid; j < e1; j += 256) {
    int2 ed = ebuf[j];
    int p = atomicAdd(&lpre[ed.y - nb0], 1);
    csr_src[e0 + p] = ed.x;
  }
}

// ---------------- per-layer kernels ----------------

// hh[n,c] = dinv[n] * sum_k X[n,k] * W[k,c]
template <int K, int C, int LOGC>
__global__ void matmul_dinv(const float* __restrict__ X, const float* __restrict__ W,
                            const float* __restrict__ dinv, float* __restrict__ hh, int n) {
  __shared__ float w[K * C];
  for (int i = threadIdx.x; i < K * C; i += 256) w[i] = W[i];
  __syncthreads();
  int idx = blockIdx.x * 256 + threadIdx.x;
  int total = n * C;
  if (idx >= total) return;
  int nn = idx >> LOGC;
  int c = idx & (C - 1);
  float acc = 0.f;
#pragma unroll
  for (int k = 0; k < K; k++) acc += X[nn * K + k] * w[k * C + c];
  hh[idx] = acc * dinv[nn];
}

// act[n, c4*4..+3] = relu(dinv[n]*(hh[n] + sum_{j in row(n)} hh[src_j]) + b)
template <int C, int LOGGP>
__global__ void gather_finalize(const float4* __restrict__ hh4, const int* __restrict__ row_start,
                                const int* __restrict__ csr_src, const float* __restrict__ dinv,
                                const float* __restrict__ bias, float4* __restrict__ act4, int n) {
  constexpr int GP = C / 4;       // float4 groups per node
  constexpr int NPB = 256 / GP;   // nodes per block
  int tid = threadIdx.x;
  int c4 = tid & (GP - 1);
  int local = tid >> LOGGP;
  int n0 = blockIdx.x * NPB + local;
  if (n0 >= n) return;

  float4 acc = hh4[n0 * GP + c4];  // self term
  int s = row_start[n0], e0 = row_start[n0 + 1];
  int j = s;
  float4 a0 = make_float4(0.f, 0.f, 0.f, 0.f);
  float4 a1 = a0, a2 = a0, a3 = a0;
  for (; j + 4 <= e0; j += 4) {
    int i0 = csr_src[j];
    int i1 = csr_src[j + 1];
    int i2 = csr_src[j + 2];
    int i3 = csr_src[j + 3];
    float4 v0 = hh4[i0 * GP + c4];
    float4 v1 = hh4[i1 * GP + c4];
    float4 v2 = hh4[i2 * GP + c4];
    float4 v3 = hh4[i3 * GP + c4];
    a0 = f4add(a0, v0);
    a1 = f4add(a1, v1);
    a2 = f4add(a2, v2);
    a3 = f4add(a3, v3);
  }
  for (; j < e0; j++) {
    int i0 = csr_src[j];
    acc = f4add(acc, hh4[i0 * GP + c4]);
  }
  acc = f4add(acc, f4add(f4add(a0, a1), f4add(a2, a3)));

  float dn = dinv[n0];
  float4 b4 = ((const float4*)bias)[c4];
  float4 v;
  v.x = fmaxf(dn * acc.x + b4.x, 0.f);
  v.y = fmaxf(dn * acc.y + b4.y, 0.f);
  v.z = fmaxf(dn * acc.z + b4.z, 0.f);
  v.w = fmaxf(dn * acc.w + b4.w, 0.f);
  act4[n0 * GP + c4] = v;
}

// per-channel sum & sumsq of act -> stats[0..C), stats[C..2C). Fixed small grid.
template <int C>
__global__ void stats_kernel(const float4* __restrict__ act4, float* __restrict__ stats, int n) {
  constexpr int GP = C / 4;
  constexpr int NPB = 256 / GP;
  int tid = threadIdx.x;
  int c4 = tid & (GP - 1);
  int local = tid / GP;
  float4 s = make_float4(0.f, 0.f, 0.f, 0.f);
  float4 q = make_float4(0.f, 0.f, 0.f, 0.f);
  for (int n0 = blockIdx.x * NPB + local; n0 < n; n0 += gridDim.x * NPB) {
    float4 v = act4[n0 * GP + c4];
    s = f4add(s, v);
    q.x += v.x * v.x; q.y += v.y * v.y; q.z += v.z * v.z; q.w += v.w * v.w;
  }
  __shared__ float4 redS[256];
  __shared__ float4 redQ[256];
  redS[tid] = s;
  redQ[tid] = q;
  __syncthreads();
#pragma unroll
  for (int off = 128; off >= GP; off >>= 1) {
    if (tid < off) {
      redS[tid] = f4add(redS[tid], redS[tid + off]);
      redQ[tid] = f4add(redQ[tid], redQ[tid + off]);
    }
    __syncthreads();
  }
  if (tid < GP) {
    atomicAdd(&stats[4 * tid + 0], redS[tid].x);
    atomicAdd(&stats[4 * tid + 1], redS[tid].y);
    atomicAdd(&stats[4 * tid + 2], redS[tid].z);
    atomicAdd(&stats[4 * tid + 3], redS[tid].w);
    atomicAdd(&stats[C + 4 * tid + 0], redQ[tid].x);
    atomicAdd(&stats[C + 4 * tid + 1], redQ[tid].y);
    atomicAdd(&stats[C + 4 * tid + 2], redQ[tid].z);
    atomicAdd(&stats[C + 4 * tid + 3], redQ[tid].w);
  }
}

// y = elu((v - mean)*rsqrt(var+eps)*g + bt), in place
template <int C>
__global__ void bn_elu(float* __restrict__ act, const float* __restrict__ stats,
                       const float* __restrict__ g, const float* __restrict__ bt, int n) {
  int i = blockIdx.x * 256 + threadIdx.x;
  int total = n * C;
  if (i >= total) return;
  int c = i & (C - 1);
  float inv_n = 1.0f / (float)n;
  float m = stats[c] * inv_n;
  float var = stats[C + c] * inv_n - m * m;
  var = fmaxf(var, 0.f);
  float sc = rsqrtf(var + BN_EPS) * g[c];
  float v = (act[i] - m) * sc + bt[c];
  act[i] = v > 0.f ? v : (expf(v) - 1.f);  // ELU
}

// ---------------- MLP head + log_softmax ----------------

__global__ void head_kernel(const float* __restrict__ h,
                            const float* __restrict__ Wf1, const float* __restrict__ bf1,
                            const float* __restrict__ Wf2, const float* __restrict__ bf2,
                            const float* __restrict__ Wf3, const float* __restrict__ bf3,
                            float* __restrict__ out, int n) {
  __shared__ float w1[64 * 32], w2[32 * 16], w3[16 * 2];
  __shared__ float sb1[32], sb2[16], sb3[2];
  for (int i = threadIdx.x; i < 64 * 32; i += 256) w1[i] = Wf1[i];
  for (int i = threadIdx.x; i < 32 * 16; i += 256) w2[i] = Wf2[i];
  if (threadIdx.x < 32) {
    w3[threadIdx.x] = Wf3[threadIdx.x];
    sb1[threadIdx.x] = bf1[threadIdx.x];
  }
  if (threadIdx.x < 16) sb2[threadIdx.x] = bf2[threadIdx.x];
  if (threadIdx.x < 2) sb3[threadIdx.x] = bf3[threadIdx.x];
  __syncthreads();

  int n0 = blockIdx.x * 256 + threadIdx.x;
  if (n0 >= n) return;

  float hv[64];
#pragma unroll
  for (int k = 0; k < 64; k++) hv[k] = h[n0 * 64 + k];

  float a1[32];
#pragma unroll
  for (int c = 0; c < 32; c++) {
    float acc = sb1[c];
#pragma unroll
    for (int k = 0; k < 64; k++) acc += hv[k] * w1[k * 32 + c];
    a1[c] = acc > 0.f ? acc : (expf(acc) - 1.f);
  }
  float a2[16];
#pragma unroll
  for (int c = 0; c < 16; c++) {
    float acc = sb2[c];
#pragma unroll
    for (int k = 0; k < 32; k++) acc += a1[k] * w2[k * 16 + c];
    a2[c] = acc > 0.f ? acc : (expf(acc) - 1.f);
  }
  float z0 = sb3[0], z1 = sb3[1];
#pragma unroll
  for (int k = 0; k < 16; k++) {
    z0 += a2[k] * w3[k * 2 + 0];
    z1 += a2[k] * w3[k * 2 + 1];
  }
  float mx = fmaxf(z0, z1);
  float lse = mx + logf(expf(z0 - mx) + expf(z1 - mx));
  out[n0 * 2 + 0] = z0 - lse;
  out[n0 * 2 + 1] = z1 - lse;
}

// ---------------- launch ----------------

extern "C" void kernel_launch(void* const* d_in, const int* in_sizes, int n_in,
                              void* d_out, int out_size, void* d_ws, size_t ws_size,
                              hipStream_t stream) {
  const float* x = (const float*)d_in[0];
  const int* ei = (const int*)d_in[1];
  const float* W1 = (const float*)d_in[2];  const float* b1 = (const float*)d_in[3];
  const float* g1 = (const float*)d_in[4];  const float* bt1 = (const float*)d_in[5];
  const float* W2 = (const float*)d_in[6];  const float* b2 = (const float*)d_in[7];
  const float* g2 = (const float*)d_in[8];  const float* bt2 = (const float*)d_in[9];
  const float* W3 = (const float*)d_in[10]; const float* b3 = (const float*)d_in[11];
  const float* g3 = (const float*)d_in[12]; const float* bt3 = (const float*)d_in[13];
  const float* Wf1 = (const float*)d_in[14]; const float* bf1 = (const float*)d_in[15];
  const float* Wf2 = (const float*)d_in[16]; const float* bf2 = (const float*)d_in[17];
  const float* Wf3 = (const float*)d_in[18]; const float* bf3 = (const float*)d_in[19];
  float* out = (float*)d_out;

  const int N = in_sizes[0] / 4;
  const int E = in_sizes[1] / 2;
  const int* srcp = ei;
  const int* dstp = ei + E;
  const int NBUCK = (N + 255) >> 8;  // <= 512 for N <= 131072

  char* ws = (char*)d_ws;
  size_t off = 0;
  auto alloc = [&](size_t bytes) {
    off = (off + 255) & ~(size_t)255;
    size_t o = off;
    off += bytes;
    return o;
  };
  float* dinv      = (float*)(ws + alloc((size_t)N * 4));
  int*   row_start = (int*)  (ws + alloc((size_t)(N + 1) * 4));
  int*   bcount    = (int*)  (ws + alloc((size_t)512 * 4));
  int*   boffset   = (int*)  (ws + alloc((size_t)513 * 4));
  int*   bcursor   = (int*)  (ws + alloc((size_t)513 * 4));
  int*   csr_src   = (int*)  (ws + alloc((size_t)E * 4));
  float* stats     = (float*)(ws + alloc((size_t)224 * 4));  // 2*16 + 2*32 + 2*64
  float* bufA      = (float*)(ws + alloc((size_t)N * 64 * 4));
  float* bufB      = (float*)(ws + alloc((size_t)N * 64 * 4));
  float* st1 = stats;       // [32]
  float* st2 = stats + 32;  // [64]
  float* st3 = stats + 96;  // [128]
  // ebuf (E int2 = 9.6 MB) aliases bufA (25.6 MB) — dead before layer-1 matmul.
  int2*  ebuf = (int2*)bufA;

  hipMemsetAsync(bcount, 0, 512 * 4, stream);
  hipMemsetAsync(stats, 0, 224 * 4, stream);

  int nb256 = (N + 255) / 256;
  const int STATS_BLOCKS = 128;

  // CSR build (bucketed, LDS-local, no global data atomics)
  hist_kernel<<<512, 256, 0, stream>>>(dstp, bcount, E);
  scan_buckets<<<1, 512, 0, stream>>>(bcount, boffset, bcursor, row_start, NBUCK, N, E);
  partition_kernel<<<(E + 4095) / 4096, 256, 0, stream>>>(srcp, dstp, bcursor, ebuf, E);
  bucket_fill<<<NBUCK, 256, 0, stream>>>(ebuf, boffset, row_start, dinv, csr_src, N);

  // Layer 1: [N,4] -> [N,16]; gather: GP=4, NPB=64
  matmul_dinv<4, 16, 4><<<(N * 16 + 255) / 256, 256, 0, stream>>>(x, W1, dinv, bufA, N);
  gather_finalize<16, 2><<<(N + 63) / 64, 256, 0, stream>>>(
      (const float4*)bufA, row_start, csr_src, dinv, b1, (float4*)bufB, N);
  stats_kernel<16><<<STATS_BLOCKS, 256, 0, stream>>>((const float4*)bufB, st1, N);
  bn_elu<16><<<(N * 16 + 255) / 256, 256, 0, stream>>>(bufB, st1, g1, bt1, N);

  // Layer 2: [N,16] -> [N,32]; gather: GP=8, NPB=32
  matmul_dinv<16, 32, 5><<<(N * 32 + 255) / 256, 256, 0, stream>>>(bufB, W2, dinv, bufA, N);
  gather_finalize<32, 3><<<(N + 31) / 32, 256, 0, stream>>>(
      (const float4*)bufA, row_start, csr_src, dinv, b2, (float4*)bufB, N);
  stats_kernel<32><<<STATS_BLOCKS, 256, 0, stream>>>((const float4*)bufB, st2, N);
  bn_elu<32><<<(N * 32 + 255) / 256, 256, 0, stream>>>(bufB, st2, g2, bt2, N);

  // Layer 3: [N,32] -> [N,64]; gather: GP=16, NPB=16
  matmul_dinv<32, 64, 6><<<(N * 64 + 255) / 256, 256, 0, stream>>>(bufB, W3, dinv, bufA, N);
  gather_finalize<64, 4><<<(N + 15) / 16, 256, 0, stream>>>(
      (const float4*)bufA, row_start, csr_src, dinv, b3, (float4*)bufB, N);
  stats_kernel<64><<<STATS_BLOCKS, 256, 0, stream>>>((const float4*)bufB, st3, N);
  bn_elu<64><<<(N * 64 + 255) / 256, 256, 0, stream>>>(bufB, st3, g3, bt3, N);

  // MLP head + log_softmax
  head_kernel<<<nb256, 256, 0, stream>>>(bufB, Wf1, bf1, Wf2, bf2, Wf3, bf3, out, N);
}